// Round 7
// baseline (200.245 us; speedup 1.0000x reference)
//
#include <hip/hip_runtime.h>
#include <hip/hip_bf16.h>

// 3-layer GCN, N=100000, E=1000000, dims 64 -> 64 -> 32 -> 16.
// s1 = x@W1 (bf16); a_k = b_k + segment_sum(w_e * s_k[col], row) (bf16);
// s_{k+1} = lrelu(a_k) @ W_{k+1}; final: out = lrelu(a_3) (f32).
// CSR built once per launch, gather-style aggregation, zero float atomics.
// R7: cnt padded to 1 counter / 128B line (R6 showed 35MB writeback on a 400KB
// array -> per-line serialization at the coherence point); EPT=8 chains in
// rank/place; scan2 folded into scan3.

__device__ __forceinline__ float lrelu(float v) { return v > 0.0f ? v : 0.25f * v; }
__device__ __forceinline__ float bflo(unsigned u) { return __uint_as_float(u << 16); }
__device__ __forceinline__ float bfhi(unsigned u) { return __uint_as_float(u & 0xffff0000u); }
__device__ __forceinline__ unsigned short f2bf(float f) {          // round-to-nearest-even
    unsigned u = __float_as_uint(f);
    return (unsigned short)((u + 0x7fffu + ((u >> 16) & 1u)) >> 16);
}
__device__ __forceinline__ unsigned packbf(float a, float b) {
    return (unsigned)f2bf(a) | ((unsigned)f2bf(b) << 16);
}

// ---------------- CSR build ----------------

constexpr int SCAN_T = 256;
constexpr int SCAN_PER = 8;
constexpr int SCAN_CHUNK = SCAN_T * SCAN_PER;  // 2048
constexpr int CPAD = 32;                       // counters padded to 128B lines

// rank[e] = atomicAdd(cnt[row[e]*CPAD], 1). EPT independent atomic chains/thread.
template <int EPT>
__global__ void __launch_bounds__(256)
rank_kernel(const int* __restrict__ row, int* __restrict__ cnt,
            int* __restrict__ rank, int E) {
    int base = blockIdx.x * (blockDim.x * EPT) + threadIdx.x;
    int r[EPT];
    int rk[EPT];
#pragma unroll
    for (int k = 0; k < EPT; ++k) {
        int e = base + k * 256;
        r[k] = (e < E) ? row[e] : -1;              // coalesced
    }
#pragma unroll
    for (int k = 0; k < EPT; ++k) {
        if (r[k] >= 0) rk[k] = atomicAdd(&cnt[(size_t)r[k] * CPAD], 1);
    }
#pragma unroll
    for (int k = 0; k < EPT; ++k) {
        int e = base + k * 256;
        if (e < E) rank[e] = rk[k];                // coalesced
    }
}

// Per-chunk inclusive scan of padded cnt into rs; chunk totals to bsum.
__global__ void __launch_bounds__(SCAN_T)
scan1_kernel(const int* __restrict__ cnt, int* __restrict__ rs,
             int* __restrict__ bsum, int N) {
    __shared__ int lds[SCAN_T];
    int t = threadIdx.x;
    int base = blockIdx.x * SCAN_CHUNK + t * SCAN_PER;
    int v[SCAN_PER];
    int run = 0;
#pragma unroll
    for (int j = 0; j < SCAN_PER; ++j) {
        int i = base + j;
        run += (i < N) ? cnt[(size_t)i * CPAD] : 0;
        v[j] = run;
    }
    lds[t] = run;
    __syncthreads();
    for (int off = 1; off < SCAN_T; off <<= 1) {
        int add = (t >= off) ? lds[t - off] : 0;
        __syncthreads();
        lds[t] += add;
        __syncthreads();
    }
    int excl = lds[t] - run;
#pragma unroll
    for (int j = 0; j < SCAN_PER; ++j) {
        int i = base + j;
        if (i < N) rs[i] = v[j] + excl;
    }
    if (t == SCAN_T - 1) bsum[blockIdx.x] = lds[t];
}

// rs += prefix(bsum); start = rs - cnt. Each block sums its own bsum prefix
// (nb <= 49; blocks of 256 lie entirely within one 2048-chunk).
__global__ void __launch_bounds__(256)
scan3_kernel(const int* __restrict__ cnt, int* __restrict__ rs,
             int* __restrict__ start, const int* __restrict__ bsum, int N) {
    int i = blockIdx.x * blockDim.x + threadIdx.x;
    if (i >= N) return;
    int chunk = i / SCAN_CHUNK;
    int bofs = 0;
    for (int c = 0; c < chunk; ++c) bofs += bsum[c];   // uniform loads, broadcast
    int e = rs[i] + bofs;
    rs[i] = e;                           // inclusive ends (agg reads these)
    start[i] = e - cnt[(size_t)i * CPAD];  // exclusive starts (place reads these)
}

// edges[start[row[e]] + rank[e]] = {col, w}. No atomics.
template <int EPT>
__global__ void __launch_bounds__(256)
place_kernel(const int* __restrict__ row, const int* __restrict__ col,
             const float* __restrict__ w, const int* __restrict__ start,
             const int* __restrict__ rank, int2* __restrict__ edges, int E) {
    int base = blockIdx.x * (blockDim.x * EPT) + threadIdx.x;
    int r[EPT], c[EPT], rk[EPT];
    float wv[EPT];
#pragma unroll
    for (int k = 0; k < EPT; ++k) {
        int e = base + k * 256;
        if (e < E) { r[k] = row[e]; c[k] = col[e]; wv[k] = w[e]; rk[k] = rank[e]; }
        else r[k] = -1;
    }
    int st[EPT];
#pragma unroll
    for (int k = 0; k < EPT; ++k) if (r[k] >= 0) st[k] = start[r[k]];   // independent gathers
#pragma unroll
    for (int k = 0; k < EPT; ++k)
        if (r[k] >= 0) edges[st[k] + rk[k]] = make_int2(c[k], __float_as_int(wv[k]));
}

// ---------------- dense transform: out = act(in) @ W, bf16 out ----------------
// NPT=4 nodes x 4 cols per thread -> each W ds_read_b128 feeds 16 FMAs.

template <int K, int M, int NPT, bool ACT, bool INBF16>
__global__ void __launch_bounds__(256)
gemm_kernel(const void* __restrict__ inv, const float* __restrict__ W,
            __hip_bfloat16* __restrict__ out, int N) {
    constexpr int QM = M / 4;
    __shared__ float Ws[K * M];
    for (int i = threadIdx.x; i < K * M / 4; i += blockDim.x)
        reinterpret_cast<float4*>(Ws)[i] = reinterpret_cast<const float4*>(W)[i];
    __syncthreads();
    int t = blockIdx.x * blockDim.x + threadIdx.x;
    int qc = t & (QM - 1);
    int ngrp = t / QM;
    int nb = ngrp * NPT;
    if (nb >= N) return;

    float acc[NPT][4];
#pragma unroll
    for (int i = 0; i < NPT; ++i) { acc[i][0] = acc[i][1] = acc[i][2] = acc[i][3] = 0.f; }

    const float* inf = (const float*)inv;
    const unsigned short* inb = (const unsigned short*)inv;

#pragma unroll
    for (int k0 = 0; k0 < K; k0 += 4) {
        float4 w0 = *reinterpret_cast<const float4*>(&Ws[(k0 + 0) * M + qc * 4]);
        float4 w1 = *reinterpret_cast<const float4*>(&Ws[(k0 + 1) * M + qc * 4]);
        float4 w2 = *reinterpret_cast<const float4*>(&Ws[(k0 + 2) * M + qc * 4]);
        float4 w3 = *reinterpret_cast<const float4*>(&Ws[(k0 + 3) * M + qc * 4]);
#pragma unroll
        for (int i = 0; i < NPT; ++i) {
            float4 xv;
            if constexpr (INBF16) {
                uint2 u = *reinterpret_cast<const uint2*>(inb + (size_t)(nb + i) * K + k0);
                xv.x = bflo(u.x); xv.y = bfhi(u.x); xv.z = bflo(u.y); xv.w = bfhi(u.y);
            } else {
                xv = *reinterpret_cast<const float4*>(inf + (size_t)(nb + i) * K + k0);
            }
            if (ACT) { xv.x = lrelu(xv.x); xv.y = lrelu(xv.y); xv.z = lrelu(xv.z); xv.w = lrelu(xv.w); }
            acc[i][0] += xv.x * w0.x + xv.y * w1.x + xv.z * w2.x + xv.w * w3.x;
            acc[i][1] += xv.x * w0.y + xv.y * w1.y + xv.z * w2.y + xv.w * w3.y;
            acc[i][2] += xv.x * w0.z + xv.y * w1.z + xv.z * w2.z + xv.w * w3.z;
            acc[i][3] += xv.x * w0.w + xv.y * w1.w + xv.z * w2.w + xv.w * w3.w;
        }
    }
#pragma unroll
    for (int i = 0; i < NPT; ++i) {
        uint2 o;
        o.x = packbf(acc[i][0], acc[i][1]);
        o.y = packbf(acc[i][2], acc[i][3]);
        *reinterpret_cast<uint2*>(out + (size_t)(nb + i) * M + qc * 4) = o;
    }
}

// ---------------- CSR aggregation: wide gathers, G = M/VPT lanes per node ----------------

template <int M, int G, bool ACTOUT, bool OUTBF16>
__global__ void __launch_bounds__(256)
agg_kernel(const int* __restrict__ rs, const int2* __restrict__ edges,
           const __hip_bfloat16* __restrict__ sup, const float* __restrict__ b,
           void* __restrict__ outv, int N) {
    constexpr int VPT = M / G;
    static_assert(VPT == 8 || VPT == 4, "VPT must be 8 or 4");
    int tid = blockIdx.x * blockDim.x + threadIdx.x;
    int node = tid / G;
    if (node >= N) return;
    int g = tid - node * G;

    float acc[VPT];
#pragma unroll
    for (int j = 0; j < VPT; ++j) acc[j] = b[g * VPT + j];

    int beg = node ? rs[node - 1] : 0;
    int end = rs[node];
    const unsigned short* su = reinterpret_cast<const unsigned short*>(sup) + g * VPT;

    for (int j0 = beg; j0 < end; j0 += G) {
        int jl = j0 + g;
        int2 ev = edges[jl < end ? jl : end - 1];   // coalesced; clamped lanes never broadcast
        int cnt = min(G, end - j0);
#pragma unroll 4
        for (int jj = 0; jj < cnt; ++jj) {
            int   col = __shfl(ev.x, jj, G);
            float w   = __int_as_float(__shfl(ev.y, jj, G));
            const unsigned short* p = su + (size_t)col * M;
            if constexpr (VPT == 8) {
                uint4 u = *reinterpret_cast<const uint4*>(p);   // 8 bf16 = 16B/lane
                acc[0] += w * bflo(u.x); acc[1] += w * bfhi(u.x);
                acc[2] += w * bflo(u.y); acc[3] += w * bfhi(u.y);
                acc[4] += w * bflo(u.z); acc[5] += w * bfhi(u.z);
                acc[6] += w * bflo(u.w); acc[7] += w * bfhi(u.w);
            } else {
                uint2 u = *reinterpret_cast<const uint2*>(p);   // 4 bf16 = 8B/lane
                acc[0] += w * bflo(u.x); acc[1] += w * bfhi(u.x);
                acc[2] += w * bflo(u.y); acc[3] += w * bfhi(u.y);
            }
        }
    }
    if (ACTOUT) {
#pragma unroll
        for (int j = 0; j < VPT; ++j) acc[j] = lrelu(acc[j]);
    }
    if constexpr (OUTBF16) {
        __hip_bfloat16* out = (__hip_bfloat16*)outv;
        if constexpr (VPT == 8) {
            uint4 o = { packbf(acc[0], acc[1]), packbf(acc[2], acc[3]),
                        packbf(acc[4], acc[5]), packbf(acc[6], acc[7]) };
            *reinterpret_cast<uint4*>(out + (size_t)node * M + g * 8) = o;
        } else {
            uint2 o = { packbf(acc[0], acc[1]), packbf(acc[2], acc[3]) };
            *reinterpret_cast<uint2*>(out + (size_t)node * M + g * 4) = o;
        }
    } else {
        float* out = (float*)outv;
        if constexpr (VPT == 8) {
            float4 o0 = {acc[0], acc[1], acc[2], acc[3]};
            float4 o1 = {acc[4], acc[5], acc[6], acc[7]};
            reinterpret_cast<float4*>(out + (size_t)node * M + g * 8)[0] = o0;
            reinterpret_cast<float4*>(out + (size_t)node * M + g * 8)[1] = o1;
        } else {
            float4 o = {acc[0], acc[1], acc[2], acc[3]};
            *reinterpret_cast<float4*>(out + (size_t)node * M + g * 4) = o;
        }
    }
}

extern "C" void kernel_launch(void* const* d_in, const int* in_sizes, int n_in,
                              void* d_out, int out_size, void* d_ws, size_t ws_size,
                              hipStream_t stream) {
    const float* x    = (const float*)d_in[0];
    const int*   erow = (const int*)  d_in[1];
    const int*   ecol = (const int*)  d_in[2];
    const float* ew   = (const float*)d_in[3];
    const float* W1   = (const float*)d_in[4];
    const float* b1   = (const float*)d_in[5];
    const float* W2   = (const float*)d_in[6];
    const float* b2   = (const float*)d_in[7];
    const float* W3   = (const float*)d_in[8];
    const float* b3   = (const float*)d_in[9];
    float* out = (float*)d_out;

    const int N = in_sizes[0] / 64;   // 100000
    const int E = in_sizes[1];        // 1000000

    // Workspace:
    //   [0,      12.8MB)  s1 (N*64 bf16); later s3 (N*16 bf16)
    //   [12.8,   25.6MB)  a1 (N*64 bf16); later a2 (N*32 bf16)
    //   [25.6,   32.0MB)  s2 (N*32 bf16)
    //   [32.0MB, ...)     CSR: cnt[N*CPAD] (12.8MB), rs[N], start[N], bsum[64],
    //                          rank[E] (4MB), edges int2[E] (8MB)   (~57.6MB total)
    char* wsc = (char*)d_ws;
    const size_t SZ64B = (size_t)N * 64 * 2;   // 12.8 MB
    const size_t SZ32B = (size_t)N * 32 * 2;   // 6.4 MB
    __hip_bfloat16* s1 = (__hip_bfloat16*)(wsc);
    __hip_bfloat16* a1 = (__hip_bfloat16*)(wsc + SZ64B);
    __hip_bfloat16* s2 = (__hip_bfloat16*)(wsc + 2 * SZ64B);
    __hip_bfloat16* a2 = (__hip_bfloat16*)(wsc + SZ64B);          // reuse a1 (dead)
    __hip_bfloat16* s3 = (__hip_bfloat16*)(wsc);                  // reuse s1 (dead)

    char* csr = wsc + 2 * SZ64B + SZ32B;
    int*  cnt   = (int*)csr;                                      // N*CPAD ints
    int*  rs    = (int*)(csr + (size_t)N * CPAD * 4);
    int*  start = rs + N;
    int*  bsum  = start + N;
    int*  rank  = bsum + 64;
    int2* edges = (int2*)(rank + E);

    const int B = 256;
    constexpr int EPT = 8;
    auto cdiv = [](long a, long b) { return (int)((a + b - 1) / b); };
    const int nb = cdiv(N, SCAN_CHUNK);

    // ---- CSR build ----
    hipMemsetAsync(cnt, 0, (size_t)N * CPAD * sizeof(int), stream);
    rank_kernel<EPT><<<cdiv(E, B * EPT), B, 0, stream>>>(erow, cnt, rank, E);
    scan1_kernel<<<nb, SCAN_T, 0, stream>>>(cnt, rs, bsum, N);
    scan3_kernel<<<cdiv(N, B), B, 0, stream>>>(cnt, rs, start, bsum, N);
    place_kernel<EPT><<<cdiv(E, B * EPT), B, 0, stream>>>(erow, ecol, ew, start, rank, edges, E);

    // ---- Layer 1: 64 -> 64 ----
    gemm_kernel<64, 64, 4, false, false><<<cdiv((long)(N / 4) * 16, B), B, 0, stream>>>(x, W1, s1, N);
    agg_kernel<64, 8, false, true><<<cdiv((long)N * 8, B), B, 0, stream>>>(rs, edges, s1, b1, a1, N);

    // ---- Layer 2: 64 -> 32 (lrelu on load) ----
    gemm_kernel<64, 32, 4, true, true><<<cdiv((long)(N / 4) * 8, B), B, 0, stream>>>(a1, W2, s2, N);
    agg_kernel<32, 4, false, true><<<cdiv((long)N * 4, B), B, 0, stream>>>(rs, edges, s2, b2, a2, N);

    // ---- Layer 3: 32 -> 16 (lrelu on load; final lrelu fused into agg) ----
    gemm_kernel<32, 16, 4, true, true><<<cdiv((long)(N / 4) * 4, B), B, 0, stream>>>(a2, W3, s3, N);
    agg_kernel<16, 4, true, false><<<cdiv((long)N * 4, B), B, 0, stream>>>(rs, edges, s3, b3, out, N);
}

// Round 8
// 172.485 us; speedup vs baseline: 1.1609x; 1.1609x over previous
//
#include <hip/hip_runtime.h>
#include <hip/hip_bf16.h>

// 3-layer GCN, N=100000, E=1000000, dims 64 -> 64 -> 32 -> 16.
// s1 = x@W1 (bf16); a_k = b_k + segment_sum(w_e * s_k[col], row) (bf16);
// s_{k+1} = lrelu(a_k) @ W_{k+1}; final: out = lrelu(a_3) (f32).
// R8: CSR build rewritten as two-level bucket counting sort with ALL counting
// in LDS (zero global atomics). R7 showed global atomicAdd caps at ~24G/s
// (42us rank) regardless of line padding or MLP depth.
//   hist1:  per-2048-edge block LDS histogram over 782 buckets (row>>7)
//   scan:   flat scan of hists[bin][blk] (382K ints), 2 tiny kernels
//   place1: LDS re-rank -> edges grouped by bucket (eb1), no atomics to global
//   place2: per-bucket block: 128-node LDS hist+scan -> final edges[] + rs[]
// agg/gemm kernels unchanged from R7 (proven correct).

__device__ __forceinline__ float lrelu(float v) { return v > 0.0f ? v : 0.25f * v; }
__device__ __forceinline__ float bflo(unsigned u) { return __uint_as_float(u << 16); }
__device__ __forceinline__ float bfhi(unsigned u) { return __uint_as_float(u & 0xffff0000u); }
__device__ __forceinline__ unsigned short f2bf(float f) {          // round-to-nearest-even
    unsigned u = __float_as_uint(f);
    return (unsigned short)((u + 0x7fffu + ((u >> 16) & 1u)) >> 16);
}
__device__ __forceinline__ unsigned packbf(float a, float b) {
    return (unsigned)f2bf(a) | ((unsigned)f2bf(b) << 16);
}

// ---------------- bucket counting-sort CSR build ----------------

constexpr int SCAN_T = 256;
constexpr int SCAN_PER = 8;
constexpr int SCAN_CHUNK = SCAN_T * SCAN_PER;  // 2048
constexpr int CHUNK = 2048;                    // edges per hist/place1 block
constexpr int BKT_BITS = 7;
constexpr int BKTSZ = 128;                     // nodes per bucket
constexpr int MAXBKT = 1024;                   // LDS bins (N <= 131072)

// hists[bin*NB + blk] = #edges of chunk blk with row>>7 == bin
__global__ void __launch_bounds__(256)
hist1_kernel(const int* __restrict__ row, int* __restrict__ hists,
             int E, int nbkt, int NB) {
    __shared__ int hist[MAXBKT];
    for (int i = threadIdx.x; i < nbkt; i += 256) hist[i] = 0;
    __syncthreads();
    int e0 = blockIdx.x * CHUNK;
    int e1 = min(e0 + CHUNK, E);
    for (int e = e0 + threadIdx.x; e < e1; e += 256)
        atomicAdd(&hist[row[e] >> BKT_BITS], 1);            // LDS atomic
    __syncthreads();
    for (int i = threadIdx.x; i < nbkt; i += 256)
        hists[(size_t)i * NB + blockIdx.x] = hist[i];
}

// per-chunk inclusive scan of the flat hist matrix (T = nbkt*NB elements)
__global__ void __launch_bounds__(SCAN_T)
scan1_kernel(int* __restrict__ I, int* __restrict__ bsum, int T) {
    __shared__ int lds[SCAN_T];
    int t = threadIdx.x;
    int base = blockIdx.x * SCAN_CHUNK + t * SCAN_PER;
    int v[SCAN_PER];
    int run = 0;
#pragma unroll
    for (int j = 0; j < SCAN_PER; ++j) {
        int i = base + j;
        run += (i < T) ? I[i] : 0;
        v[j] = run;
    }
    lds[t] = run;
    __syncthreads();
    for (int off = 1; off < SCAN_T; off <<= 1) {
        int add = (t >= off) ? lds[t - off] : 0;
        __syncthreads();
        lds[t] += add;
        __syncthreads();
    }
    int excl = lds[t] - run;
#pragma unroll
    for (int j = 0; j < SCAN_PER; ++j) {
        int i = base + j;
        if (i < T) I[i] = v[j] + excl;
    }
    if (t == SCAN_T - 1) bsum[blockIdx.x] = lds[t];
}

__global__ void __launch_bounds__(64)
scan2_kernel(const int* __restrict__ bsum, int* __restrict__ bofs, int nb) {
    if (threadIdx.x == 0 && blockIdx.x == 0) {
        int run = 0;
        for (int i = 0; i < nb; ++i) { bofs[i] = run; run += bsum[i]; }
    }
}

__device__ __forceinline__ int getI(const int* __restrict__ I,
                                    const int* __restrict__ bofs, size_t idx) {
    return I[idx] + bofs[idx >> 11];    // 2048-element chunks
}

// place edges into bucket-contiguous eb1; pos = (scanned excl base) + LDS rank.
__global__ void __launch_bounds__(256)
place1_kernel(const int* __restrict__ row, const int* __restrict__ col,
              const float* __restrict__ w, const int* __restrict__ I,
              const int* __restrict__ bofs, int2* __restrict__ eb1,
              int E, int nbkt, int NB) {
    __shared__ int srow[CHUNK];
    __shared__ int hist[MAXBKT];
    for (int i = threadIdx.x; i < nbkt; i += 256) hist[i] = 0;
    int e0 = blockIdx.x * CHUNK;
    int e1 = min(e0 + CHUNK, E);
    for (int e = e0 + threadIdx.x; e < e1; e += 256) srow[e - e0] = row[e];
    __syncthreads();
    for (int i = threadIdx.x; i < e1 - e0; i += 256)
        atomicAdd(&hist[srow[i] >> BKT_BITS], 1);
    __syncthreads();
    // hist[bin] <- global exclusive base for (bin, thisblock)
    for (int i = threadIdx.x; i < nbkt; i += 256) {
        size_t idx = (size_t)i * NB + blockIdx.x;
        hist[i] = getI(I, bofs, idx) - hist[i];
    }
    __syncthreads();
    for (int e = e0 + threadIdx.x; e < e1; e += 256) {
        int r = srow[e - e0];
        int pos = atomicAdd(&hist[r >> BKT_BITS], 1);        // LDS atomic, returns slot
        eb1[pos] = make_int2(((r & (BKTSZ - 1)) << 20) | col[e], __float_as_int(w[e]));
    }
}

// one block per bucket: exact per-node CSR within the bucket; emits edges[] + rs[].
__global__ void __launch_bounds__(256)
place2_kernel(const int2* __restrict__ eb1, const int* __restrict__ I,
              const int* __restrict__ bofs, int2* __restrict__ edges,
              int* __restrict__ rs, int N, int NB) {
    __shared__ int hist[BKTSZ];
    __shared__ int scanv[BKTSZ];
    int b = blockIdx.x;
    int t = threadIdx.x;
    int bstart = (b == 0) ? 0 : getI(I, bofs, (size_t)b * NB - 1);
    int bend   = getI(I, bofs, (size_t)(b + 1) * NB - 1);
    if (t < BKTSZ) hist[t] = 0;
    __syncthreads();
    for (int e = bstart + t; e < bend; e += 256)
        atomicAdd(&hist[(eb1[e].x >> 20) & (BKTSZ - 1)], 1);
    __syncthreads();
    int cval = (t < BKTSZ) ? hist[t] : 0;
    if (t < BKTSZ) scanv[t] = cval;
    __syncthreads();
    for (int off = 1; off < BKTSZ; off <<= 1) {
        int add = (t < BKTSZ && t >= off) ? scanv[t - off] : 0;
        __syncthreads();
        if (t < BKTSZ) scanv[t] += add;
        __syncthreads();
    }
    if (t < BKTSZ) {
        int gnode = b * BKTSZ + t;
        if (gnode < N) rs[gnode] = bstart + scanv[t];        // inclusive ends
        hist[t] = bstart + scanv[t] - cval;                  // node base for placing
    }
    __syncthreads();
    for (int e = bstart + t; e < bend; e += 256) {
        int2 ev = eb1[e];
        int lrow = (ev.x >> 20) & (BKTSZ - 1);
        int pos = atomicAdd(&hist[lrow], 1);                 // LDS atomic
        edges[pos] = make_int2(ev.x & 0xFFFFF, ev.y);        // {col, w_bits}
    }
}

// ---------------- dense transform: out = act(in) @ W, bf16 out (unchanged) ----------------

template <int K, int M, int NPT, bool ACT, bool INBF16>
__global__ void __launch_bounds__(256)
gemm_kernel(const void* __restrict__ inv, const float* __restrict__ W,
            __hip_bfloat16* __restrict__ out, int N) {
    constexpr int QM = M / 4;
    __shared__ float Ws[K * M];
    for (int i = threadIdx.x; i < K * M / 4; i += blockDim.x)
        reinterpret_cast<float4*>(Ws)[i] = reinterpret_cast<const float4*>(W)[i];
    __syncthreads();
    int t = blockIdx.x * blockDim.x + threadIdx.x;
    int qc = t & (QM - 1);
    int ngrp = t / QM;
    int nb = ngrp * NPT;
    if (nb >= N) return;

    float acc[NPT][4];
#pragma unroll
    for (int i = 0; i < NPT; ++i) { acc[i][0] = acc[i][1] = acc[i][2] = acc[i][3] = 0.f; }

    const float* inf = (const float*)inv;
    const unsigned short* inb = (const unsigned short*)inv;

#pragma unroll
    for (int k0 = 0; k0 < K; k0 += 4) {
        float4 w0 = *reinterpret_cast<const float4*>(&Ws[(k0 + 0) * M + qc * 4]);
        float4 w1 = *reinterpret_cast<const float4*>(&Ws[(k0 + 1) * M + qc * 4]);
        float4 w2 = *reinterpret_cast<const float4*>(&Ws[(k0 + 2) * M + qc * 4]);
        float4 w3 = *reinterpret_cast<const float4*>(&Ws[(k0 + 3) * M + qc * 4]);
#pragma unroll
        for (int i = 0; i < NPT; ++i) {
            float4 xv;
            if constexpr (INBF16) {
                uint2 u = *reinterpret_cast<const uint2*>(inb + (size_t)(nb + i) * K + k0);
                xv.x = bflo(u.x); xv.y = bfhi(u.x); xv.z = bflo(u.y); xv.w = bfhi(u.y);
            } else {
                xv = *reinterpret_cast<const float4*>(inf + (size_t)(nb + i) * K + k0);
            }
            if (ACT) { xv.x = lrelu(xv.x); xv.y = lrelu(xv.y); xv.z = lrelu(xv.z); xv.w = lrelu(xv.w); }
            acc[i][0] += xv.x * w0.x + xv.y * w1.x + xv.z * w2.x + xv.w * w3.x;
            acc[i][1] += xv.x * w0.y + xv.y * w1.y + xv.z * w2.y + xv.w * w3.y;
            acc[i][2] += xv.x * w0.z + xv.y * w1.z + xv.z * w2.z + xv.w * w3.z;
            acc[i][3] += xv.x * w0.w + xv.y * w1.w + xv.z * w2.w + xv.w * w3.w;
        }
    }
#pragma unroll
    for (int i = 0; i < NPT; ++i) {
        uint2 o;
        o.x = packbf(acc[i][0], acc[i][1]);
        o.y = packbf(acc[i][2], acc[i][3]);
        *reinterpret_cast<uint2*>(out + (size_t)(nb + i) * M + qc * 4) = o;
    }
}

// ---------------- CSR aggregation (unchanged) ----------------

template <int M, int G, bool ACTOUT, bool OUTBF16>
__global__ void __launch_bounds__(256)
agg_kernel(const int* __restrict__ rs, const int2* __restrict__ edges,
           const __hip_bfloat16* __restrict__ sup, const float* __restrict__ b,
           void* __restrict__ outv, int N) {
    constexpr int VPT = M / G;
    static_assert(VPT == 8 || VPT == 4, "VPT must be 8 or 4");
    int tid = blockIdx.x * blockDim.x + threadIdx.x;
    int node = tid / G;
    if (node >= N) return;
    int g = tid - node * G;

    float acc[VPT];
#pragma unroll
    for (int j = 0; j < VPT; ++j) acc[j] = b[g * VPT + j];

    int beg = node ? rs[node - 1] : 0;
    int end = rs[node];
    const unsigned short* su = reinterpret_cast<const unsigned short*>(sup) + g * VPT;

    for (int j0 = beg; j0 < end; j0 += G) {
        int jl = j0 + g;
        int2 ev = edges[jl < end ? jl : end - 1];   // coalesced; clamped lanes never broadcast
        int cnt = min(G, end - j0);
#pragma unroll 4
        for (int jj = 0; jj < cnt; ++jj) {
            int   col = __shfl(ev.x, jj, G);
            float w   = __int_as_float(__shfl(ev.y, jj, G));
            const unsigned short* p = su + (size_t)col * M;
            if constexpr (VPT == 8) {
                uint4 u = *reinterpret_cast<const uint4*>(p);   // 8 bf16 = 16B/lane
                acc[0] += w * bflo(u.x); acc[1] += w * bfhi(u.x);
                acc[2] += w * bflo(u.y); acc[3] += w * bfhi(u.y);
                acc[4] += w * bflo(u.z); acc[5] += w * bfhi(u.z);
                acc[6] += w * bflo(u.w); acc[7] += w * bfhi(u.w);
            } else {
                uint2 u = *reinterpret_cast<const uint2*>(p);   // 4 bf16 = 8B/lane
                acc[0] += w * bflo(u.x); acc[1] += w * bfhi(u.x);
                acc[2] += w * bflo(u.y); acc[3] += w * bfhi(u.y);
            }
        }
    }
    if (ACTOUT) {
#pragma unroll
        for (int j = 0; j < VPT; ++j) acc[j] = lrelu(acc[j]);
    }
    if constexpr (OUTBF16) {
        __hip_bfloat16* out = (__hip_bfloat16*)outv;
        if constexpr (VPT == 8) {
            uint4 o = { packbf(acc[0], acc[1]), packbf(acc[2], acc[3]),
                        packbf(acc[4], acc[5]), packbf(acc[6], acc[7]) };
            *reinterpret_cast<uint4*>(out + (size_t)node * M + g * 8) = o;
        } else {
            uint2 o = { packbf(acc[0], acc[1]), packbf(acc[2], acc[3]) };
            *reinterpret_cast<uint2*>(out + (size_t)node * M + g * 4) = o;
        }
    } else {
        float* out = (float*)outv;
        if constexpr (VPT == 8) {
            float4 o0 = {acc[0], acc[1], acc[2], acc[3]};
            float4 o1 = {acc[4], acc[5], acc[6], acc[7]};
            reinterpret_cast<float4*>(out + (size_t)node * M + g * 8)[0] = o0;
            reinterpret_cast<float4*>(out + (size_t)node * M + g * 8)[1] = o1;
        } else {
            float4 o = {acc[0], acc[1], acc[2], acc[3]};
            *reinterpret_cast<float4*>(out + (size_t)node * M + g * 4) = o;
        }
    }
}

extern "C" void kernel_launch(void* const* d_in, const int* in_sizes, int n_in,
                              void* d_out, int out_size, void* d_ws, size_t ws_size,
                              hipStream_t stream) {
    const float* x    = (const float*)d_in[0];
    const int*   erow = (const int*)  d_in[1];
    const int*   ecol = (const int*)  d_in[2];
    const float* ew   = (const float*)d_in[3];
    const float* W1   = (const float*)d_in[4];
    const float* b1   = (const float*)d_in[5];
    const float* W2   = (const float*)d_in[6];
    const float* b2   = (const float*)d_in[7];
    const float* W3   = (const float*)d_in[8];
    const float* b3   = (const float*)d_in[9];
    float* out = (float*)d_out;

    const int N = in_sizes[0] / 64;   // 100000
    const int E = in_sizes[1];        // 1000000

    auto cdiv = [](long a, long b) { return (int)((a + b - 1) / b); };
    const int NB   = cdiv(E, CHUNK);          // 489 edge chunks
    const int nbkt = cdiv(N, BKTSZ);          // 782 buckets
    const long T   = (long)nbkt * NB;         // 382,398 flat hist entries
    const int nsc  = cdiv(T, SCAN_CHUNK);     // 187 scan chunks

    // Workspace:
    //   [0,      12.8MB)  s1 (N*64 bf16); later s3 (N*16 bf16)
    //   [12.8,   25.6MB)  a1 (N*64 bf16); later a2 (N*32 bf16)
    //   [25.6,   32.0MB)  s2 (N*32 bf16)
    //   [32.0MB, ...)     I[T] (1.6MB), bsum[256], bofs[256], rs[N] (0.4MB),
    //                     eb1[E] int2 (8MB), edges[E] int2 (8MB)   (~50MB total)
    char* wsc = (char*)d_ws;
    const size_t SZ64B = (size_t)N * 64 * 2;   // 12.8 MB
    const size_t SZ32B = (size_t)N * 32 * 2;   // 6.4 MB
    __hip_bfloat16* s1 = (__hip_bfloat16*)(wsc);
    __hip_bfloat16* a1 = (__hip_bfloat16*)(wsc + SZ64B);
    __hip_bfloat16* s2 = (__hip_bfloat16*)(wsc + 2 * SZ64B);
    __hip_bfloat16* a2 = (__hip_bfloat16*)(wsc + SZ64B);          // reuse a1 (dead)
    __hip_bfloat16* s3 = (__hip_bfloat16*)(wsc);                  // reuse s1 (dead)

    char* csr = wsc + 2 * SZ64B + SZ32B;
    int*  I     = (int*)csr;                       // T ints
    int*  bsum  = I + T;
    int*  bofs  = bsum + 256;
    int*  rs    = bofs + 256;                      // N ints
    int2* eb1   = (int2*)(rs + N);                 // E int2
    int2* edges = eb1 + E;                         // E int2

    const int B = 256;

    // ---- CSR build (no global atomics) ----
    hist1_kernel<<<NB, B, 0, stream>>>(erow, I, E, nbkt, NB);
    scan1_kernel<<<nsc, SCAN_T, 0, stream>>>(I, bsum, (int)T);
    scan2_kernel<<<1, 64, 0, stream>>>(bsum, bofs, nsc);
    place1_kernel<<<NB, B, 0, stream>>>(erow, ecol, ew, I, bofs, eb1, E, nbkt, NB);
    place2_kernel<<<nbkt, B, 0, stream>>>(eb1, I, bofs, edges, rs, N, NB);

    // ---- Layer 1: 64 -> 64 ----
    gemm_kernel<64, 64, 4, false, false><<<cdiv((long)(N / 4) * 16, B), B, 0, stream>>>(x, W1, s1, N);
    agg_kernel<64, 8, false, true><<<cdiv((long)N * 8, B), B, 0, stream>>>(rs, edges, s1, b1, a1, N);

    // ---- Layer 2: 64 -> 32 (lrelu on load) ----
    gemm_kernel<64, 32, 4, true, true><<<cdiv((long)(N / 4) * 8, B), B, 0, stream>>>(a1, W2, s2, N);
    agg_kernel<32, 4, false, true><<<cdiv((long)N * 4, B), B, 0, stream>>>(rs, edges, s2, b2, a2, N);

    // ---- Layer 3: 32 -> 16 (lrelu on load; final lrelu fused into agg) ----
    gemm_kernel<32, 16, 4, true, true><<<cdiv((long)(N / 4) * 4, B), B, 0, stream>>>(a2, W3, s3, N);
    agg_kernel<16, 4, true, false><<<cdiv((long)N * 4, B), B, 0, stream>>>(rs, edges, s3, b3, out, N);
}

// Round 9
// 159.072 us; speedup vs baseline: 1.2588x; 1.0843x over previous
//
#include <hip/hip_runtime.h>
#include <hip/hip_bf16.h>

// 3-layer GCN, N=100000, E=1000000, dims 64 -> 64 -> 32 -> 16.
// s1 = x@W1 (bf16); a_k = b_k + segment_sum(w_e * s_k[col], row) (bf16);
// s_{k+1} = lrelu(a_k) @ W_{k+1}; final: out = lrelu(a_3) (f32).
// CSR via two-level LDS bucket counting sort (zero global atomics, R8).
// R9: dispatch consolidation — hist1 fused with gemm1 (independent work, one
// launch); scan2 folded into place1/place2 as an LDS prefix of bsum; CHUNK
// 2048->4096 halves the flat hist matrix. agg/gemm bodies unchanged.

__device__ __forceinline__ float lrelu(float v) { return v > 0.0f ? v : 0.25f * v; }
__device__ __forceinline__ float bflo(unsigned u) { return __uint_as_float(u << 16); }
__device__ __forceinline__ float bfhi(unsigned u) { return __uint_as_float(u & 0xffff0000u); }
__device__ __forceinline__ unsigned short f2bf(float f) {          // round-to-nearest-even
    unsigned u = __float_as_uint(f);
    return (unsigned short)((u + 0x7fffu + ((u >> 16) & 1u)) >> 16);
}
__device__ __forceinline__ unsigned packbf(float a, float b) {
    return (unsigned)f2bf(a) | ((unsigned)f2bf(b) << 16);
}

// ---------------- bucket counting-sort CSR build ----------------

constexpr int SCAN_T = 256;
constexpr int SCAN_PER = 8;
constexpr int SCAN_CHUNK = SCAN_T * SCAN_PER;  // 2048 (scan1 granularity; getI >>11)
constexpr int CHUNK = 4096;                    // edges per hist/place1 block
constexpr int BKT_BITS = 7;
constexpr int BKTSZ = 128;                     // nodes per bucket
constexpr int MAXBKT = 1024;                   // LDS bins (N <= 131072)
constexpr int MAXNSC = 128;                    // max scan1 chunks (T <= 262144)

// Build exclusive prefix of bsum[0..nsc-1] into bofs[] (LDS), nsc <= 128.
__device__ __forceinline__ void build_bofs(const int* __restrict__ bsum, int nsc,
                                           int* tmp, int* bofs) {
    int t = threadIdx.x;
    int v = (t < MAXNSC && t < nsc) ? bsum[t] : 0;
    if (t < MAXNSC) tmp[t] = v;
    __syncthreads();
    for (int off = 1; off < MAXNSC; off <<= 1) {
        int add = (t < MAXNSC && t >= off) ? tmp[t - off] : 0;
        __syncthreads();
        if (t < MAXNSC) tmp[t] += add;
        __syncthreads();
    }
    if (t < MAXNSC) bofs[t] = tmp[t] - v;   // exclusive
    __syncthreads();
}

__device__ __forceinline__ int getI(const int* __restrict__ I,
                                    const int* __restrict__ bofs, size_t idx) {
    return I[idx] + bofs[idx >> 11];    // 2048-element scan chunks
}

// ---------------- dense transform body: out = act(in) @ W, bf16 out ----------------
// NPT=4 nodes x 4 cols per thread -> each W ds_read_b128 feeds 16 FMAs.

template <int K, int M, int NPT, bool ACT, bool INBF16>
__device__ __forceinline__ void
gemm_body(const void* __restrict__ inv, const float* __restrict__ W,
          __hip_bfloat16* __restrict__ out, int N, int gblk, float* Ws) {
    constexpr int QM = M / 4;
    for (int i = threadIdx.x; i < K * M / 4; i += 256)
        reinterpret_cast<float4*>(Ws)[i] = reinterpret_cast<const float4*>(W)[i];
    __syncthreads();
    int t = gblk * 256 + threadIdx.x;
    int qc = t & (QM - 1);
    int ngrp = t / QM;
    int nb = ngrp * NPT;
    if (nb >= N) return;

    float acc[NPT][4];
#pragma unroll
    for (int i = 0; i < NPT; ++i) { acc[i][0] = acc[i][1] = acc[i][2] = acc[i][3] = 0.f; }

    const float* inf = (const float*)inv;
    const unsigned short* inb = (const unsigned short*)inv;

#pragma unroll
    for (int k0 = 0; k0 < K; k0 += 4) {
        float4 w0 = *reinterpret_cast<const float4*>(&Ws[(k0 + 0) * M + qc * 4]);
        float4 w1 = *reinterpret_cast<const float4*>(&Ws[(k0 + 1) * M + qc * 4]);
        float4 w2 = *reinterpret_cast<const float4*>(&Ws[(k0 + 2) * M + qc * 4]);
        float4 w3 = *reinterpret_cast<const float4*>(&Ws[(k0 + 3) * M + qc * 4]);
#pragma unroll
        for (int i = 0; i < NPT; ++i) {
            float4 xv;
            if constexpr (INBF16) {
                uint2 u = *reinterpret_cast<const uint2*>(inb + (size_t)(nb + i) * K + k0);
                xv.x = bflo(u.x); xv.y = bfhi(u.x); xv.z = bflo(u.y); xv.w = bfhi(u.y);
            } else {
                xv = *reinterpret_cast<const float4*>(inf + (size_t)(nb + i) * K + k0);
            }
            if (ACT) { xv.x = lrelu(xv.x); xv.y = lrelu(xv.y); xv.z = lrelu(xv.z); xv.w = lrelu(xv.w); }
            acc[i][0] += xv.x * w0.x + xv.y * w1.x + xv.z * w2.x + xv.w * w3.x;
            acc[i][1] += xv.x * w0.y + xv.y * w1.y + xv.z * w2.y + xv.w * w3.y;
            acc[i][2] += xv.x * w0.z + xv.y * w1.z + xv.z * w2.z + xv.w * w3.z;
            acc[i][3] += xv.x * w0.w + xv.y * w1.w + xv.z * w2.w + xv.w * w3.w;
        }
    }
#pragma unroll
    for (int i = 0; i < NPT; ++i) {
        uint2 o;
        o.x = packbf(acc[i][0], acc[i][1]);
        o.y = packbf(acc[i][2], acc[i][3]);
        *reinterpret_cast<uint2*>(out + (size_t)(nb + i) * M + qc * 4) = o;
    }
}

template <int K, int M, int NPT, bool ACT, bool INBF16>
__global__ void __launch_bounds__(256)
gemm_kernel(const void* __restrict__ inv, const float* __restrict__ W,
            __hip_bfloat16* __restrict__ out, int N) {
    __shared__ float Ws[K * M];
    gemm_body<K, M, NPT, ACT, INBF16>(inv, W, out, N, blockIdx.x, Ws);
}

// ---------------- fused: hist1 (blocks [0,NB)) + gemm1 (blocks [NB,...)) ----------------

__global__ void __launch_bounds__(256)
fused_hist_gemm1_kernel(const int* __restrict__ row, int* __restrict__ hists,
                        int E, int nbkt, int NB,
                        const float* __restrict__ x, const float* __restrict__ W1,
                        __hip_bfloat16* __restrict__ s1, int N) {
    __shared__ float Ws[64 * 64];   // 16KB; hist role reuses it as int bins
    if ((int)blockIdx.x < NB) {
        int* hist = reinterpret_cast<int*>(Ws);
        for (int i = threadIdx.x; i < nbkt; i += 256) hist[i] = 0;
        __syncthreads();
        int e0 = blockIdx.x * CHUNK;
        int e1 = min(e0 + CHUNK, E);
        for (int e = e0 + threadIdx.x; e < e1; e += 256)
            atomicAdd(&hist[row[e] >> BKT_BITS], 1);         // LDS atomic
        __syncthreads();
        for (int i = threadIdx.x; i < nbkt; i += 256)
            hists[(size_t)i * NB + blockIdx.x] = hist[i];
    } else {
        gemm_body<64, 64, 4, false, false>(x, W1, s1, N, blockIdx.x - NB, Ws);
    }
}

// per-chunk inclusive scan of the flat hist matrix (T = nbkt*NB elements)
__global__ void __launch_bounds__(SCAN_T)
scan1_kernel(int* __restrict__ I, int* __restrict__ bsum, int T) {
    __shared__ int lds[SCAN_T];
    int t = threadIdx.x;
    int base = blockIdx.x * SCAN_CHUNK + t * SCAN_PER;
    int v[SCAN_PER];
    int run = 0;
#pragma unroll
    for (int j = 0; j < SCAN_PER; ++j) {
        int i = base + j;
        run += (i < T) ? I[i] : 0;
        v[j] = run;
    }
    lds[t] = run;
    __syncthreads();
    for (int off = 1; off < SCAN_T; off <<= 1) {
        int add = (t >= off) ? lds[t - off] : 0;
        __syncthreads();
        lds[t] += add;
        __syncthreads();
    }
    int excl = lds[t] - run;
#pragma unroll
    for (int j = 0; j < SCAN_PER; ++j) {
        int i = base + j;
        if (i < T) I[i] = v[j] + excl;
    }
    if (t == SCAN_T - 1) bsum[blockIdx.x] = lds[t];
}

// place edges into bucket-contiguous eb1; pos = (scanned excl base) + LDS rank.
__global__ void __launch_bounds__(256)
place1_kernel(const int* __restrict__ row, const int* __restrict__ col,
              const float* __restrict__ w, const int* __restrict__ I,
              const int* __restrict__ bsum, int nsc, int2* __restrict__ eb1,
              int E, int nbkt, int NB) {
    __shared__ int srow[CHUNK];
    __shared__ int hist[MAXBKT];
    __shared__ int tmp[MAXNSC];
    __shared__ int bofs[MAXNSC];
    build_bofs(bsum, nsc, tmp, bofs);
    for (int i = threadIdx.x; i < nbkt; i += 256) hist[i] = 0;
    int e0 = blockIdx.x * CHUNK;
    int e1 = min(e0 + CHUNK, E);
    for (int e = e0 + threadIdx.x; e < e1; e += 256) srow[e - e0] = row[e];
    __syncthreads();
    for (int i = threadIdx.x; i < e1 - e0; i += 256)
        atomicAdd(&hist[srow[i] >> BKT_BITS], 1);
    __syncthreads();
    // hist[bin] <- global exclusive base for (bin, thisblock)
    for (int i = threadIdx.x; i < nbkt; i += 256) {
        size_t idx = (size_t)i * NB + blockIdx.x;
        hist[i] = getI(I, bofs, idx) - hist[i];
    }
    __syncthreads();
    for (int e = e0 + threadIdx.x; e < e1; e += 256) {
        int r = srow[e - e0];
        int pos = atomicAdd(&hist[r >> BKT_BITS], 1);        // LDS atomic, returns slot
        eb1[pos] = make_int2(((r & (BKTSZ - 1)) << 20) | col[e], __float_as_int(w[e]));
    }
}

// one block per bucket: exact per-node CSR within the bucket; emits edges[] + rs[].
__global__ void __launch_bounds__(256)
place2_kernel(const int2* __restrict__ eb1, const int* __restrict__ I,
              const int* __restrict__ bsum, int nsc, int2* __restrict__ edges,
              int* __restrict__ rs, int N, int NB) {
    __shared__ int hist[BKTSZ];
    __shared__ int scanv[BKTSZ];
    __shared__ int tmp[MAXNSC];
    __shared__ int bofs[MAXNSC];
    build_bofs(bsum, nsc, tmp, bofs);
    int b = blockIdx.x;
    int t = threadIdx.x;
    int bstart = (b == 0) ? 0 : getI(I, bofs, (size_t)b * NB - 1);
    int bend   = getI(I, bofs, (size_t)(b + 1) * NB - 1);
    if (t < BKTSZ) hist[t] = 0;
    __syncthreads();
    for (int e = bstart + t; e < bend; e += 256)
        atomicAdd(&hist[(eb1[e].x >> 20) & (BKTSZ - 1)], 1);
    __syncthreads();
    int cval = (t < BKTSZ) ? hist[t] : 0;
    if (t < BKTSZ) scanv[t] = cval;
    __syncthreads();
    for (int off = 1; off < BKTSZ; off <<= 1) {
        int add = (t < BKTSZ && t >= off) ? scanv[t - off] : 0;
        __syncthreads();
        if (t < BKTSZ) scanv[t] += add;
        __syncthreads();
    }
    if (t < BKTSZ) {
        int gnode = b * BKTSZ + t;
        if (gnode < N) rs[gnode] = bstart + scanv[t];        // inclusive ends
        hist[t] = bstart + scanv[t] - cval;                  // node base for placing
    }
    __syncthreads();
    for (int e = bstart + t; e < bend; e += 256) {
        int2 ev = eb1[e];
        int lrow = (ev.x >> 20) & (BKTSZ - 1);
        int pos = atomicAdd(&hist[lrow], 1);                 // LDS atomic
        edges[pos] = make_int2(ev.x & 0xFFFFF, ev.y);        // {col, w_bits}
    }
}

// ---------------- CSR aggregation: wide gathers, G = M/VPT lanes per node ----------------

template <int M, int G, bool ACTOUT, bool OUTBF16>
__global__ void __launch_bounds__(256)
agg_kernel(const int* __restrict__ rs, const int2* __restrict__ edges,
           const __hip_bfloat16* __restrict__ sup, const float* __restrict__ b,
           void* __restrict__ outv, int N) {
    constexpr int VPT = M / G;
    static_assert(VPT == 8 || VPT == 4, "VPT must be 8 or 4");
    int tid = blockIdx.x * blockDim.x + threadIdx.x;
    int node = tid / G;
    if (node >= N) return;
    int g = tid - node * G;

    float acc[VPT];
#pragma unroll
    for (int j = 0; j < VPT; ++j) acc[j] = b[g * VPT + j];

    int beg = node ? rs[node - 1] : 0;
    int end = rs[node];
    const unsigned short* su = reinterpret_cast<const unsigned short*>(sup) + g * VPT;

    for (int j0 = beg; j0 < end; j0 += G) {
        int jl = j0 + g;
        int2 ev = edges[jl < end ? jl : end - 1];   // coalesced; clamped lanes never broadcast
        int cnt = min(G, end - j0);
#pragma unroll 4
        for (int jj = 0; jj < cnt; ++jj) {
            int   col = __shfl(ev.x, jj, G);
            float w   = __int_as_float(__shfl(ev.y, jj, G));
            const unsigned short* p = su + (size_t)col * M;
            if constexpr (VPT == 8) {
                uint4 u = *reinterpret_cast<const uint4*>(p);   // 8 bf16 = 16B/lane
                acc[0] += w * bflo(u.x); acc[1] += w * bfhi(u.x);
                acc[2] += w * bflo(u.y); acc[3] += w * bfhi(u.y);
                acc[4] += w * bflo(u.z); acc[5] += w * bfhi(u.z);
                acc[6] += w * bflo(u.w); acc[7] += w * bfhi(u.w);
            } else {
                uint2 u = *reinterpret_cast<const uint2*>(p);   // 4 bf16 = 8B/lane
                acc[0] += w * bflo(u.x); acc[1] += w * bfhi(u.x);
                acc[2] += w * bflo(u.y); acc[3] += w * bfhi(u.y);
            }
        }
    }
    if (ACTOUT) {
#pragma unroll
        for (int j = 0; j < VPT; ++j) acc[j] = lrelu(acc[j]);
    }
    if constexpr (OUTBF16) {
        __hip_bfloat16* out = (__hip_bfloat16*)outv;
        if constexpr (VPT == 8) {
            uint4 o = { packbf(acc[0], acc[1]), packbf(acc[2], acc[3]),
                        packbf(acc[4], acc[5]), packbf(acc[6], acc[7]) };
            *reinterpret_cast<uint4*>(out + (size_t)node * M + g * 8) = o;
        } else {
            uint2 o = { packbf(acc[0], acc[1]), packbf(acc[2], acc[3]) };
            *reinterpret_cast<uint2*>(out + (size_t)node * M + g * 4) = o;
        }
    } else {
        float* out = (float*)outv;
        if constexpr (VPT == 8) {
            float4 o0 = {acc[0], acc[1], acc[2], acc[3]};
            float4 o1 = {acc[4], acc[5], acc[6], acc[7]};
            reinterpret_cast<float4*>(out + (size_t)node * M + g * 8)[0] = o0;
            reinterpret_cast<float4*>(out + (size_t)node * M + g * 8)[1] = o1;
        } else {
            float4 o = {acc[0], acc[1], acc[2], acc[3]};
            *reinterpret_cast<float4*>(out + (size_t)node * M + g * 4) = o;
        }
    }
}

extern "C" void kernel_launch(void* const* d_in, const int* in_sizes, int n_in,
                              void* d_out, int out_size, void* d_ws, size_t ws_size,
                              hipStream_t stream) {
    const float* x    = (const float*)d_in[0];
    const int*   erow = (const int*)  d_in[1];
    const int*   ecol = (const int*)  d_in[2];
    const float* ew   = (const float*)d_in[3];
    const float* W1   = (const float*)d_in[4];
    const float* b1   = (const float*)d_in[5];
    const float* W2   = (const float*)d_in[6];
    const float* b2   = (const float*)d_in[7];
    const float* W3   = (const float*)d_in[8];
    const float* b3   = (const float*)d_in[9];
    float* out = (float*)d_out;

    const int N = in_sizes[0] / 64;   // 100000
    const int E = in_sizes[1];        // 1000000

    auto cdiv = [](long a, long b) { return (int)((a + b - 1) / b); };
    const int NB   = cdiv(E, CHUNK);          // 245 edge chunks
    const int nbkt = cdiv(N, BKTSZ);          // 782 buckets
    const long T   = (long)nbkt * NB;         // 191,590 flat hist entries
    const int nsc  = cdiv(T, SCAN_CHUNK);     // 94 scan chunks (<= MAXNSC)

    // Workspace:
    //   [0,      12.8MB)  s1 (N*64 bf16); later s3 (N*16 bf16)
    //   [12.8,   25.6MB)  a1 (N*64 bf16); later a2 (N*32 bf16)
    //   [25.6,   32.0MB)  s2 (N*32 bf16)
    //   [32.0MB, ...)     I[T] (0.8MB), bsum[128], rs[N] (0.4MB),
    //                     eb1[E] int2 (8MB), edges[E] int2 (8MB)
    char* wsc = (char*)d_ws;
    const size_t SZ64B = (size_t)N * 64 * 2;   // 12.8 MB
    const size_t SZ32B = (size_t)N * 32 * 2;   // 6.4 MB
    __hip_bfloat16* s1 = (__hip_bfloat16*)(wsc);
    __hip_bfloat16* a1 = (__hip_bfloat16*)(wsc + SZ64B);
    __hip_bfloat16* s2 = (__hip_bfloat16*)(wsc + 2 * SZ64B);
    __hip_bfloat16* a2 = (__hip_bfloat16*)(wsc + SZ64B);          // reuse a1 (dead)
    __hip_bfloat16* s3 = (__hip_bfloat16*)(wsc);                  // reuse s1 (dead)

    char* csr = wsc + 2 * SZ64B + SZ32B;
    int*  I     = (int*)csr;                       // T ints
    int*  bsum  = I + T;                           // MAXNSC ints
    int*  rs    = bsum + MAXNSC;                   // N ints
    int2* eb1   = (int2*)(rs + N);                 // E int2
    int2* edges = eb1 + E;                         // E int2

    const int B = 256;
    const int G1 = cdiv((long)(N / 4) * 16, B);    // gemm1 blocks (1563)

    // ---- CSR build (no global atomics) + gemm1 overlapped ----
    fused_hist_gemm1_kernel<<<NB + G1, B, 0, stream>>>(erow, I, E, nbkt, NB, x, W1, s1, N);
    scan1_kernel<<<nsc, SCAN_T, 0, stream>>>(I, bsum, (int)T);
    place1_kernel<<<NB, B, 0, stream>>>(erow, ecol, ew, I, bsum, nsc, eb1, E, nbkt, NB);
    place2_kernel<<<nbkt, B, 0, stream>>>(eb1, I, bsum, nsc, edges, rs, N, NB);

    // ---- Layer 1 aggregation ----
    agg_kernel<64, 8, false, true><<<cdiv((long)N * 8, B), B, 0, stream>>>(rs, edges, s1, b1, a1, N);

    // ---- Layer 2: 64 -> 32 (lrelu on load) ----
    gemm_kernel<64, 32, 4, true, true><<<cdiv((long)(N / 4) * 8, B), B, 0, stream>>>(a1, W2, s2, N);
    agg_kernel<32, 4, false, true><<<cdiv((long)N * 4, B), B, 0, stream>>>(rs, edges, s2, b2, a2, N);

    // ---- Layer 3: 32 -> 16 (lrelu on load; final lrelu fused into agg) ----
    gemm_kernel<32, 16, 4, true, true><<<cdiv((long)(N / 4) * 4, B), B, 0, stream>>>(a2, W3, s3, N);
    agg_kernel<16, 4, true, false><<<cdiv((long)N * 4, B), B, 0, stream>>>(rs, edges, s3, b3, out, N);
}